// Round 1
// baseline (225.297 us; speedup 1.0000x reference)
//
#include <hip/hip_runtime.h>
#include <hip/hip_bf16.h>

#define BB 2
#define TT 2048
#define CC 1024
#define NHEAD 16
#define DHEAD 64
#define MM (BB*TT)

using bf16 = __hip_bfloat16;
typedef __bf16 bf16x8 __attribute__((ext_vector_type(8)));
typedef float f32x4 __attribute__((ext_vector_type(4)));

static __device__ __forceinline__ bf16 f2b(float f) { return __float2bfloat16(f); }

// ---------------- fp32 -> bf16 linear convert (vectorized) ----------------
__global__ void k_convert(const float* __restrict__ in, bf16* __restrict__ out, int n4) {
  int i = blockIdx.x * blockDim.x + threadIdx.x;
  if (i >= n4) return;
  float4 v = reinterpret_cast<const float4*>(in)[i];
  bf16 o[4] = { f2b(v.x), f2b(v.y), f2b(v.z), f2b(v.w) };
  reinterpret_cast<uint2*>(out)[i] = *reinterpret_cast<uint2*>(o);
}

// ------------- fp32 (R x Cc) -> bf16 transposed (Cc x R) -------------
__global__ void k_transpose(const float* __restrict__ W, bf16* __restrict__ WT, int R, int Cc) {
  __shared__ float tile[32][33];
  int c0 = blockIdx.x * 32, r0 = blockIdx.y * 32;
  int tx = threadIdx.x, ty = threadIdx.y;   // 32 x 8
#pragma unroll
  for (int i = 0; i < 4; ++i)
    tile[ty + 8*i][tx] = W[(size_t)(r0 + ty + 8*i) * Cc + c0 + tx];
  __syncthreads();
#pragma unroll
  for (int i = 0; i < 4; ++i)
    WT[(size_t)(c0 + ty + 8*i) * R + r0 + tx] = f2b(tile[tx][ty + 8*i]);
}

// ---------------- 128x128 bf16 GEMM, A (MxK) row-major, Bt (NxK) row-major ----------------
// MODE 0: qkv epilogue (scatter to Q/K/V in (B,N,T,D), Q pre-scaled by 1/8)
// MODE 1: fp32 out + bias, row-major MxCC
template<int MODE>
__global__ __launch_bounds__(256)
void k_gemm(const bf16* __restrict__ A, const bf16* __restrict__ Bt,
            const float* __restrict__ bias, float* __restrict__ outF,
            bf16* __restrict__ Qb, bf16* __restrict__ Kb, bf16* __restrict__ Vb,
            int K)
{
  const int tid  = threadIdx.x;
  const int wave = tid >> 6, lane = tid & 63;
  const int l16 = lane & 15, l4 = lane >> 4;
  const int wr = wave >> 1, wc = wave & 1;
  const int m0 = blockIdx.y * 128, n0 = blockIdx.x * 128;

  __shared__ __align__(16) bf16 As[128][40];   // +8 pad: 80B row stride, 16B aligned
  __shared__ __align__(16) bf16 Bs[128][40];

  f32x4 acc[4][4];
#pragma unroll
  for (int m = 0; m < 4; ++m)
#pragma unroll
    for (int n = 0; n < 4; ++n) acc[m][n] = 0.f;

  const int srow = tid >> 2;          // 0..63
  const int scol = (tid & 3) * 8;     // 0,8,16,24

  for (int k0 = 0; k0 < K; k0 += 32) {
    __syncthreads();
#pragma unroll
    for (int i = 0; i < 2; ++i) {
      bf16x8 av = *reinterpret_cast<const bf16x8*>(&A[(size_t)(m0 + i*64 + srow) * K + k0 + scol]);
      *reinterpret_cast<bf16x8*>(&As[i*64 + srow][scol]) = av;
      bf16x8 bv = *reinterpret_cast<const bf16x8*>(&Bt[(size_t)(n0 + i*64 + srow) * K + k0 + scol]);
      *reinterpret_cast<bf16x8*>(&Bs[i*64 + srow][scol]) = bv;
    }
    __syncthreads();
    bf16x8 af[4], bfr[4];
#pragma unroll
    for (int m = 0; m < 4; ++m)
      af[m] = *reinterpret_cast<const bf16x8*>(&As[wr*64 + m*16 + l16][l4*8]);
#pragma unroll
    for (int n = 0; n < 4; ++n)
      bfr[n] = *reinterpret_cast<const bf16x8*>(&Bs[wc*64 + n*16 + l16][l4*8]);
#pragma unroll
    for (int m = 0; m < 4; ++m)
#pragma unroll
      for (int n = 0; n < 4; ++n)
        acc[m][n] = __builtin_amdgcn_mfma_f32_16x16x32_bf16(af[m], bfr[n], acc[m][n], 0, 0, 0);
  }

  if (MODE == 0) {
    const int which = n0 >> 10;                 // uniform per block (tile within one C-chunk)
    bf16* __restrict__ dst = (which == 0) ? Qb : (which == 1) ? Kb : Vb;
    const float qsc = (which == 0) ? 0.125f : 1.0f;   // fold 1/sqrt(D) into Q (exact pow2)
#pragma unroll
    for (int m = 0; m < 4; ++m)
#pragma unroll
      for (int n = 0; n < 4; ++n)
#pragma unroll
        for (int j = 0; j < 4; ++j) {
          int gr = m0 + wr*64 + m*16 + l4*4 + j;
          int gc = n0 + wc*64 + n*16 + l16;
          float val = (acc[m][n][j] + bias[gc]) * qsc;
          int c = gc & (CC-1), head = c >> 6, d = c & 63;
          int b = gr >> 11, t = gr & (TT-1);
          dst[(((size_t)b*NHEAD + head)*TT + t)*DHEAD + d] = f2b(val);
        }
  } else {
#pragma unroll
    for (int m = 0; m < 4; ++m)
#pragma unroll
      for (int n = 0; n < 4; ++n)
#pragma unroll
        for (int j = 0; j < 4; ++j) {
          int gr = m0 + wr*64 + m*16 + l4*4 + j;
          int gc = n0 + wc*64 + n*16 + l16;
          outF[(size_t)gr * CC + gc] = acc[m][n][j] + bias[gc];
        }
  }
}

// ---------------- flash attention (full softmax; mask in ref is +1e-9, i.e. no-op) ----------------
// grid: (TT/128, BB*NHEAD); 4 waves x 32 q-rows each; KV tiles of 64.
__global__ __launch_bounds__(256)
void k_attn(const bf16* __restrict__ Qg, const bf16* __restrict__ Kg,
            const bf16* __restrict__ Vg, bf16* __restrict__ Aout)
{
  const int tid  = threadIdx.x;
  const int wave = tid >> 6, lane = tid & 63;
  const int l16 = lane & 15, l4 = lane >> 4;
  const int bn = blockIdx.y;
  const int b = bn >> 4, h = bn & (NHEAD-1);
  const int q0 = blockIdx.x * 128;

  __shared__ __align__(16) bf16 Ks[64][72];      // K tile row-major, padded (144B stride)
  __shared__ __align__(16) bf16 Vt[64][72];      // V tile transposed [d][kv], padded
  __shared__ __align__(16) bf16 Pl[4][32][72];   // per-wave P scratch, padded

  const size_t hb = (size_t)bn * TT * DHEAD;

  // Q fragments held in registers for the whole kernel (Q already scaled by 1/8)
  bf16x8 qf[2][2];
#pragma unroll
  for (int m = 0; m < 2; ++m)
#pragma unroll
    for (int kk = 0; kk < 2; ++kk)
      qf[m][kk] = *reinterpret_cast<const bf16x8*>(
          &Qg[hb + (size_t)(q0 + wave*32 + m*16 + l16) * DHEAD + kk*32 + l4*8]);

  f32x4 o[2][4];
  float mrun[2][4], lrun[2][4];
#pragma unroll
  for (int m = 0; m < 2; ++m)
#pragma unroll
    for (int n = 0; n < 4; ++n) o[m][n] = 0.f;
#pragma unroll
  for (int m = 0; m < 2; ++m)
#pragma unroll
    for (int j = 0; j < 4; ++j) { mrun[m][j] = -1e30f; lrun[m][j] = 0.f; }

  const int sr = tid >> 2;          // 0..63
  const int sc = (tid & 3) * 16;    // 0,16,32,48

  for (int t0 = 0; t0 < TT; t0 += 64) {
    __syncthreads();
    {
      const bf16* kg = &Kg[hb + (size_t)(t0 + sr) * DHEAD + sc];
      *reinterpret_cast<bf16x8*>(&Ks[sr][sc])     = *reinterpret_cast<const bf16x8*>(kg);
      *reinterpret_cast<bf16x8*>(&Ks[sr][sc + 8]) = *reinterpret_cast<const bf16x8*>(kg + 8);
      const bf16* vg = &Vg[hb + (size_t)(t0 + sr) * DHEAD + sc];
      bf16x8 v0 = *reinterpret_cast<const bf16x8*>(vg);
      bf16x8 v1 = *reinterpret_cast<const bf16x8*>(vg + 8);
#pragma unroll
      for (int i = 0; i < 8; ++i) Vt[sc + i][sr]     = ((bf16*)&v0)[i];
#pragma unroll
      for (int i = 0; i < 8; ++i) Vt[sc + 8 + i][sr] = ((bf16*)&v1)[i];
    }
    __syncthreads();

    // S = Q K^T (raw scores; scale folded into Q)
    f32x4 s[2][4];
#pragma unroll
    for (int m = 0; m < 2; ++m)
#pragma unroll
      for (int n = 0; n < 4; ++n) s[m][n] = 0.f;

    bf16x8 kf[4][2];
#pragma unroll
    for (int n = 0; n < 4; ++n)
#pragma unroll
      for (int kk = 0; kk < 2; ++kk)
        kf[n][kk] = *reinterpret_cast<const bf16x8*>(&Ks[n*16 + l16][kk*32 + l4*8]);
#pragma unroll
    for (int m = 0; m < 2; ++m)
#pragma unroll
      for (int n = 0; n < 4; ++n)
#pragma unroll
        for (int kk = 0; kk < 2; ++kk)
          s[m][n] = __builtin_amdgcn_mfma_f32_16x16x32_bf16(qf[m][kk], kf[n][kk], s[m][n], 0, 0, 0);

    // online softmax; row r of fragment m lives in lanes with l4 == (r%16)/4, j = r%4
#pragma unroll
    for (int m = 0; m < 2; ++m) {
      float pm[4];
#pragma unroll
      for (int j = 0; j < 4; ++j)
        pm[j] = fmaxf(fmaxf(s[m][0][j], s[m][1][j]), fmaxf(s[m][2][j], s[m][3][j]));
#pragma unroll
      for (int off = 1; off < 16; off <<= 1)
#pragma unroll
        for (int j = 0; j < 4; ++j)
          pm[j] = fmaxf(pm[j], __shfl_xor(pm[j], off, 64));
#pragma unroll
      for (int j = 0; j < 4; ++j) {
        float mn = fmaxf(mrun[m][j], pm[j]);
        float corr = __expf(mrun[m][j] - mn);
        mrun[m][j] = mn;
        lrun[m][j] *= corr;
#pragma unroll
        for (int n = 0; n < 4; ++n) o[m][n][j] *= corr;
        pm[j] = mn;
      }
      float ps[4] = {0.f, 0.f, 0.f, 0.f};
#pragma unroll
      for (int n = 0; n < 4; ++n)
#pragma unroll
        for (int j = 0; j < 4; ++j) {
          float pv = __expf(s[m][n][j] - pm[j]);
          s[m][n][j] = pv;
          ps[j] += pv;
        }
#pragma unroll
      for (int off = 1; off < 16; off <<= 1)
#pragma unroll
        for (int j = 0; j < 4; ++j)
          ps[j] += __shfl_xor(ps[j], off, 64);
#pragma unroll
      for (int j = 0; j < 4; ++j) lrun[m][j] += ps[j];
      // P -> per-wave LDS (bf16) for the PV MFMA A-operand
#pragma unroll
      for (int n = 0; n < 4; ++n)
#pragma unroll
        for (int j = 0; j < 4; ++j)
          Pl[wave][m*16 + l4*4 + j][n*16 + l16] = f2b(s[m][n][j]);
    }

    // O += P V
#pragma unroll
    for (int m = 0; m < 2; ++m) {
      bf16x8 pf[2];
#pragma unroll
      for (int kk = 0; kk < 2; ++kk)
        pf[kk] = *reinterpret_cast<const bf16x8*>(&Pl[wave][m*16 + l16][kk*32 + l4*8]);
#pragma unroll
      for (int n = 0; n < 4; ++n)
#pragma unroll
        for (int kk = 0; kk < 2; ++kk) {
          bf16x8 vf = *reinterpret_cast<const bf16x8*>(&Vt[n*16 + l16][kk*32 + l4*8]);
          o[m][n] = __builtin_amdgcn_mfma_f32_16x16x32_bf16(pf[kk], vf, o[m][n], 0, 0, 0);
        }
    }
  }

  // epilogue: normalize and store to (B,T,C) bf16 for the proj GEMM
#pragma unroll
  for (int m = 0; m < 2; ++m)
#pragma unroll
    for (int j = 0; j < 4; ++j) {
      float inv = 1.0f / lrun[m][j];
      int gt = q0 + wave*32 + m*16 + l4*4 + j;
#pragma unroll
      for (int n = 0; n < 4; ++n)
        Aout[((size_t)(b*TT + gt))*CC + h*DHEAD + n*16 + l16] = f2b(o[m][n][j] * inv);
    }
}

extern "C" void kernel_launch(void* const* d_in, const int* in_sizes, int n_in,
                              void* d_out, int out_size, void* d_ws, size_t ws_size,
                              hipStream_t stream)
{
  const float* x     = (const float*)d_in[0];
  const float* Wqkv  = (const float*)d_in[1];
  const float* bqkv  = (const float*)d_in[2];
  const float* Wproj = (const float*)d_in[3];
  const float* bproj = (const float*)d_in[4];
  float* out = (float*)d_out;

  char* p = (char*)d_ws;
  bf16* Xb     = (bf16*)p;  p += (size_t)MM*CC*2;        // 8 MB
  bf16* WqkvT  = (bf16*)p;  p += (size_t)3*CC*CC*2;      // 6 MB   (3C x C, N-major)
  bf16* WprojT = (bf16*)p;  p += (size_t)CC*CC*2;        // 2 MB   (C x C, N-major)
  bf16* Qb     = (bf16*)p;  p += (size_t)MM*CC*2;        // 8 MB   (B,N,T,D)
  bf16* Kb     = (bf16*)p;  p += (size_t)MM*CC*2;        // 8 MB
  bf16* Vb     = (bf16*)p;  p += (size_t)MM*CC*2;        // 8 MB
  bf16* Attn   = (bf16*)p;  p += (size_t)MM*CC*2;        // 8 MB   (B,T,C)

  k_convert<<<(MM*CC/4 + 255)/256, 256, 0, stream>>>(x, Xb, MM*CC/4);
  k_transpose<<<dim3(3*CC/32, CC/32), dim3(32, 8), 0, stream>>>(Wqkv, WqkvT, CC, 3*CC);
  k_transpose<<<dim3(CC/32, CC/32), dim3(32, 8), 0, stream>>>(Wproj, WprojT, CC, CC);

  k_gemm<0><<<dim3(3*CC/128, MM/128), 256, 0, stream>>>(Xb, WqkvT, bqkv, nullptr, Qb, Kb, Vb, CC);
  k_attn<<<dim3(TT/128, BB*NHEAD), 256, 0, stream>>>(Qb, Kb, Vb, Attn);
  k_gemm<1><<<dim3(CC/128, MM/128), 256, 0, stream>>>(Attn, WprojT, bproj, out, nullptr, nullptr, nullptr, CC);
}

// Round 3
// 172.166 us; speedup vs baseline: 1.3086x; 1.3086x over previous
//
#include <hip/hip_runtime.h>
#include <hip/hip_bf16.h>

#define BB 2
#define TT 2048
#define CC 1024
#define NHEAD 16
#define DHEAD 64
#define MM (BB*TT)

using bf16 = __hip_bfloat16;
typedef __bf16 bf16x8 __attribute__((ext_vector_type(8)));
typedef __bf16 bf16x4 __attribute__((ext_vector_type(4)));
typedef float f32x4 __attribute__((ext_vector_type(4)));

static __device__ __forceinline__ bf16 f2b(float f) { return __float2bfloat16(f); }
static __device__ __forceinline__ float fast_exp2(float f) { return __builtin_amdgcn_exp2f(f); }

// ---------------- fp32 -> bf16 linear convert (vectorized) ----------------
__global__ void k_convert(const float* __restrict__ in, bf16* __restrict__ out, int n4) {
  int i = blockIdx.x * blockDim.x + threadIdx.x;
  if (i >= n4) return;
  float4 v = reinterpret_cast<const float4*>(in)[i];
  bf16 o[4] = { f2b(v.x), f2b(v.y), f2b(v.z), f2b(v.w) };
  reinterpret_cast<uint2*>(out)[i] = *reinterpret_cast<uint2*>(o);
}

// ------------- fp32 (R x Cc) -> bf16 transposed (Cc x R) -------------
__global__ void k_transpose(const float* __restrict__ W, bf16* __restrict__ WT, int R, int Cc) {
  __shared__ float tile[32][33];
  int c0 = blockIdx.x * 32, r0 = blockIdx.y * 32;
  int tx = threadIdx.x, ty = threadIdx.y;   // 32 x 8
#pragma unroll
  for (int i = 0; i < 4; ++i)
    tile[ty + 8*i][tx] = W[(size_t)(r0 + ty + 8*i) * Cc + c0 + tx];
  __syncthreads();
#pragma unroll
  for (int i = 0; i < 4; ++i)
    WT[(size_t)(c0 + ty + 8*i) * R + r0 + tx] = f2b(tile[tx][ty + 8*i]);
}

// ------------- per-head V (T x D) -> V^T (D x T), bf16 -------------
__global__ void k_vtrans(const bf16* __restrict__ V, bf16* __restrict__ VT) {
  __shared__ bf16 tile[32][33];
  const int bn = blockIdx.z;
  const int d0 = blockIdx.x * 32, t0 = blockIdx.y * 32;
  const size_t base = (size_t)bn * TT * DHEAD;
  int tx = threadIdx.x, ty = threadIdx.y;   // 32 x 8
#pragma unroll
  for (int i = 0; i < 4; ++i)
    tile[ty + 8*i][tx] = V[base + (size_t)(t0 + ty + 8*i) * DHEAD + d0 + tx];
  __syncthreads();
#pragma unroll
  for (int i = 0; i < 4; ++i)
    VT[base + (size_t)(d0 + ty + 8*i) * TT + t0 + tx] = tile[tx][ty + 8*i];
}

// ---------------- 128x128 bf16 GEMM, A (MxK) row-major, Bt (NxK) row-major ----------------
// MODE 0: qkv epilogue (scatter to Q/K/V in (B,N,T,D); Q pre-scaled by log2e/sqrt(D))
// MODE 1: fp32 out + bias, row-major MxCC
template<int MODE>
__global__ __launch_bounds__(256)
void k_gemm(const bf16* __restrict__ A, const bf16* __restrict__ Bt,
            const float* __restrict__ bias, float* __restrict__ outF,
            bf16* __restrict__ Qb, bf16* __restrict__ Kb, bf16* __restrict__ Vb,
            int K)
{
  const int tid  = threadIdx.x;
  const int wave = tid >> 6, lane = tid & 63;
  const int l16 = lane & 15, l4 = lane >> 4;
  const int wr = wave >> 1, wc = wave & 1;
  const int m0 = blockIdx.y * 128, n0 = blockIdx.x * 128;

  __shared__ __align__(16) bf16 As[128][40];   // +8 pad
  __shared__ __align__(16) bf16 Bs[128][40];

  f32x4 acc[4][4];
#pragma unroll
  for (int m = 0; m < 4; ++m)
#pragma unroll
    for (int n = 0; n < 4; ++n) acc[m][n] = 0.f;

  const int srow = tid >> 2;          // 0..63
  const int scol = (tid & 3) * 8;     // 0,8,16,24

  for (int k0 = 0; k0 < K; k0 += 32) {
    __syncthreads();
#pragma unroll
    for (int i = 0; i < 2; ++i) {
      bf16x8 av = *reinterpret_cast<const bf16x8*>(&A[(size_t)(m0 + i*64 + srow) * K + k0 + scol]);
      *reinterpret_cast<bf16x8*>(&As[i*64 + srow][scol]) = av;
      bf16x8 bv = *reinterpret_cast<const bf16x8*>(&Bt[(size_t)(n0 + i*64 + srow) * K + k0 + scol]);
      *reinterpret_cast<bf16x8*>(&Bs[i*64 + srow][scol]) = bv;
    }
    __syncthreads();
    bf16x8 af[4], bfr[4];
#pragma unroll
    for (int m = 0; m < 4; ++m)
      af[m] = *reinterpret_cast<const bf16x8*>(&As[wr*64 + m*16 + l16][l4*8]);
#pragma unroll
    for (int n = 0; n < 4; ++n)
      bfr[n] = *reinterpret_cast<const bf16x8*>(&Bs[wc*64 + n*16 + l16][l4*8]);
#pragma unroll
    for (int m = 0; m < 4; ++m)
#pragma unroll
      for (int n = 0; n < 4; ++n)
        acc[m][n] = __builtin_amdgcn_mfma_f32_16x16x32_bf16(af[m], bfr[n], acc[m][n], 0, 0, 0);
  }

  if (MODE == 0) {
    const int which = n0 >> 10;
    bf16* __restrict__ dst = (which == 0) ? Qb : (which == 1) ? Kb : Vb;
    // fold 1/sqrt(D) AND log2(e) into Q so attention can use exp2
    const float qsc = (which == 0) ? 0.125f * 1.4426950408889634f : 1.0f;
#pragma unroll
    for (int m = 0; m < 4; ++m)
#pragma unroll
      for (int n = 0; n < 4; ++n)
#pragma unroll
        for (int j = 0; j < 4; ++j) {
          int gr = m0 + wr*64 + m*16 + l4*4 + j;
          int gc = n0 + wc*64 + n*16 + l16;
          float val = (acc[m][n][j] + bias[gc]) * qsc;
          int c = gc & (CC-1), head = c >> 6, d = c & 63;
          int b = gr >> 11, t = gr & (TT-1);
          dst[(((size_t)b*NHEAD + head)*TT + t)*DHEAD + d] = f2b(val);
        }
  } else {
#pragma unroll
    for (int m = 0; m < 4; ++m)
#pragma unroll
      for (int n = 0; n < 4; ++n)
#pragma unroll
        for (int j = 0; j < 4; ++j) {
          int gr = m0 + wr*64 + m*16 + l4*4 + j;
          int gc = n0 + wc*64 + n*16 + l16;
          outF[(size_t)gr * CC + gc] = acc[m][n][j] + bias[gc];
        }
  }
}

// ---------------- flash attention, swapped-QK^T in-register softmax ----------------
// grid: (TT/64, BB*NHEAD); 4 waves, each owns 16 q-rows; KV tiles of 64.
// Q pre-scaled by 0.125*log2(e) -> softmax in exp2 domain.
__global__ __launch_bounds__(256, 4)
void k_attn(const bf16* __restrict__ Qg, const bf16* __restrict__ Kg,
            const bf16* __restrict__ VTg, bf16* __restrict__ Aout)
{
  const int tid  = threadIdx.x;
  const int wave = tid >> 6, lane = tid & 63;
  const int l16 = lane & 15, l4 = lane >> 4;
  const int bn = blockIdx.y;
  const int b = bn >> 4, h = bn & (NHEAD-1);
  const int q0 = blockIdx.x * 64;

  __shared__ __align__(16) bf16 Ks[64][72];      // K tile [kv][d], padded (144B stride, 2-way free)
  __shared__ __align__(16) bf16 Vt[64][72];      // V^T tile [d][kv], padded
  __shared__ __align__(16) bf16 Pl[4][16][72];   // per-wave P[q][kv]

  const size_t hb = (size_t)bn * TT * DHEAD;

  // Q fragments (B-operand of swapped QK): lane l16 holds Q[q0+w*16+l16][kk*32+l4*8..+7]
  bf16x8 qf[2];
#pragma unroll
  for (int kk = 0; kk < 2; ++kk)
    qf[kk] = *reinterpret_cast<const bf16x8*>(
        &Qg[hb + (size_t)(q0 + wave*16 + l16) * DHEAD + kk*32 + l4*8]);

  f32x4 o[4];
#pragma unroll
  for (int n = 0; n < 4; ++n) o[n] = 0.f;
  float mrun = -1e30f, lrun = 0.f;   // per-lane: stats for q = l16 (replicated across l4)

  const int sr = tid >> 2;          // 0..63
  const int sc = (tid & 3) * 16;    // 0,16,32,48

  for (int t0 = 0; t0 < TT; t0 += 64) {
    __syncthreads();
    {
      const bf16* kg = &Kg[hb + (size_t)(t0 + sr) * DHEAD + sc];
      *reinterpret_cast<bf16x8*>(&Ks[sr][sc])     = *reinterpret_cast<const bf16x8*>(kg);
      *reinterpret_cast<bf16x8*>(&Ks[sr][sc + 8]) = *reinterpret_cast<const bf16x8*>(kg + 8);
      const bf16* vg = &VTg[hb + (size_t)sr * TT + t0 + sc];
      *reinterpret_cast<bf16x8*>(&Vt[sr][sc])     = *reinterpret_cast<const bf16x8*>(vg);
      *reinterpret_cast<bf16x8*>(&Vt[sr][sc + 8]) = *reinterpret_cast<const bf16x8*>(vg + 8);
    }
    __syncthreads();

    // S^T = K Q^T : lane holds S^T[kv = n*16 + l4*4 + j][q = l16]
    f32x4 s[4];
#pragma unroll
    for (int n = 0; n < 4; ++n) s[n] = 0.f;
    __builtin_amdgcn_s_setprio(1);
#pragma unroll
    for (int n = 0; n < 4; ++n) {
      bf16x8 kf0 = *reinterpret_cast<const bf16x8*>(&Ks[n*16 + l16][l4*8]);
      bf16x8 kf1 = *reinterpret_cast<const bf16x8*>(&Ks[n*16 + l16][32 + l4*8]);
      s[n] = __builtin_amdgcn_mfma_f32_16x16x32_bf16(kf0, qf[0], s[n], 0, 0, 0);
      s[n] = __builtin_amdgcn_mfma_f32_16x16x32_bf16(kf1, qf[1], s[n], 0, 0, 0);
    }
    __builtin_amdgcn_s_setprio(0);

    // --- online softmax, exp2 domain, per-lane over 16 kv values ---
    float pm = s[0][0];
#pragma unroll
    for (int n = 0; n < 4; ++n)
#pragma unroll
      for (int j = 0; j < 4; ++j) pm = fmaxf(pm, s[n][j]);
    pm = fmaxf(pm, __shfl_xor(pm, 16, 64));
    pm = fmaxf(pm, __shfl_xor(pm, 32, 64));

    float mn = fmaxf(mrun, pm);
    float corr = fast_exp2(mrun - mn);
    mrun = mn;

    float psum = 0.f;
#pragma unroll
    for (int n = 0; n < 4; ++n) {
      bf16x4 pk;
#pragma unroll
      for (int j = 0; j < 4; ++j) {
        float pv = fast_exp2(s[n][j] - mn);
        psum += pv;
        pk[j] = (__bf16)pv;
      }
      *reinterpret_cast<bf16x4*>(&Pl[wave][l16][n*16 + l4*4]) = pk;
    }
    psum += __shfl_xor(psum, 16, 64);
    psum += __shfl_xor(psum, 32, 64);
    lrun = lrun * corr + psum;

    // broadcast corr from softmax-lane (q = l16) to O-row lanes (q = l4*4+j)
    float cj[4];
#pragma unroll
    for (int j = 0; j < 4; ++j)
      cj[j] = __shfl(corr, ((lane >> 4) << 2) + j, 64);
#pragma unroll
    for (int n = 0; n < 4; ++n)
#pragma unroll
      for (int j = 0; j < 4; ++j) o[n][j] *= cj[j];

    // O += P V  (A = P[q][kv] from per-wave LDS, B = V^T[d][kv])
    bf16x8 pf0 = *reinterpret_cast<const bf16x8*>(&Pl[wave][l16][l4*8]);
    bf16x8 pf1 = *reinterpret_cast<const bf16x8*>(&Pl[wave][l16][32 + l4*8]);
    __builtin_amdgcn_s_setprio(1);
#pragma unroll
    for (int n = 0; n < 4; ++n) {
      bf16x8 vf0 = *reinterpret_cast<const bf16x8*>(&Vt[n*16 + l16][l4*8]);
      bf16x8 vf1 = *reinterpret_cast<const bf16x8*>(&Vt[n*16 + l16][32 + l4*8]);
      o[n] = __builtin_amdgcn_mfma_f32_16x16x32_bf16(pf0, vf0, o[n], 0, 0, 0);
      o[n] = __builtin_amdgcn_mfma_f32_16x16x32_bf16(pf1, vf1, o[n], 0, 0, 0);
    }
    __builtin_amdgcn_s_setprio(0);
  }

  // epilogue: broadcast 1/l from softmax lanes to O-row lanes, store (B,T,C)
  float linv = 1.0f / lrun;
  float lj[4];
#pragma unroll
  for (int j = 0; j < 4; ++j)
    lj[j] = __shfl(linv, ((lane >> 4) << 2) + j, 64);
#pragma unroll
  for (int j = 0; j < 4; ++j) {
    int gt = q0 + wave*16 + l4*4 + j;
#pragma unroll
    for (int n = 0; n < 4; ++n)
      Aout[((size_t)(b*TT + gt))*CC + h*DHEAD + n*16 + l16] = f2b(o[n][j] * lj[j]);
  }
}

extern "C" void kernel_launch(void* const* d_in, const int* in_sizes, int n_in,
                              void* d_out, int out_size, void* d_ws, size_t ws_size,
                              hipStream_t stream)
{
  const float* x     = (const float*)d_in[0];
  const float* Wqkv  = (const float*)d_in[1];
  const float* bqkv  = (const float*)d_in[2];
  const float* Wproj = (const float*)d_in[3];
  const float* bproj = (const float*)d_in[4];
  float* out = (float*)d_out;

  char* p = (char*)d_ws;
  bf16* Xb     = (bf16*)p;  p += (size_t)MM*CC*2;        // 8 MB (dead after QKV GEMM)
  bf16* WqkvT  = (bf16*)p;  p += (size_t)3*CC*CC*2;      // 6 MB
  bf16* WprojT = (bf16*)p;  p += (size_t)CC*CC*2;        // 2 MB
  bf16* Qb     = (bf16*)p;  p += (size_t)MM*CC*2;        // 8 MB (B,N,T,D)
  bf16* Kb     = (bf16*)p;  p += (size_t)MM*CC*2;        // 8 MB
  bf16* Vb     = (bf16*)p;  p += (size_t)MM*CC*2;        // 8 MB
  bf16* Attn   = (bf16*)p;  p += (size_t)MM*CC*2;        // 8 MB (B,T,C)
  bf16* VTb    = Xb;                                     // reuse Xb: (B,N,D,T)

  k_convert<<<(MM*CC/4 + 255)/256, 256, 0, stream>>>(x, Xb, MM*CC/4);
  k_transpose<<<dim3(3*CC/32, CC/32), dim3(32, 8), 0, stream>>>(Wqkv, WqkvT, CC, 3*CC);
  k_transpose<<<dim3(CC/32, CC/32), dim3(32, 8), 0, stream>>>(Wproj, WprojT, CC, CC);

  k_gemm<0><<<dim3(3*CC/128, MM/128), 256, 0, stream>>>(Xb, WqkvT, bqkv, nullptr, Qb, Kb, Vb, CC);
  k_vtrans<<<dim3(DHEAD/32, TT/32, BB*NHEAD), dim3(32, 8), 0, stream>>>(Vb, VTb);
  k_attn<<<dim3(TT/64, BB*NHEAD), 256, 0, stream>>>(Qb, Kb, VTb, Attn);
  k_gemm<1><<<dim3(CC/128, MM/128), 256, 0, stream>>>(Attn, WprojT, bproj, out, nullptr, nullptr, nullptr, CC);
}